// Round 4
// baseline (179.598 us; speedup 1.0000x reference)
//
#include <hip/hip_runtime.h>
#include <hip/hip_bf16.h>

// 2D-MDLSTM (4 directions) + FC head for MI355X — round 19.
//
// R18 confirmed the budget: total 146.1 = mdlstm 84.3 + fc ~3 + ~59 us fixed
// launch/gap overhead (fusion triple-falsified at >= +48 us in-kernel).
//
// R19 theory: per step (3670 cyc) no pipe exceeds ~40% (MFMA-active ~918
// cyc/SIMD, non-MFMA VALU ~1030 [VALUBusy counts MFMA issue!], LDS ~1360
// CU-wide, stall ~47%): the kernel is PHASE-serialized — all 8 waves burst
// LDS, then MFMA, then trans in lockstep, so wall ~= SUM of phases.
// Lever: 2 independent WGs/CU with uncorrelated barriers -> phases overlap
// across WGs (sum -> max). BT=1: one batch per WG, 512 WGs x 512 thr,
// LDS ~31 KB -> 2 WGs/CU co-resident (62K of 160K LDS, 92 VGPR = 4
// waves/SIMD). In-WG structure is R12 verbatim (diagonal-relative mapping,
// same step/math); only the batch dim moved from in-WG (BT=2) to grid.
// Cost: dummy-row padding 27%->59% (+26% per-CU pipe work) — affordable on
// half-idle pipes; max tasks/wave/step 2->1. Parity s_sleep staggers
// CU-sharing WGs toward anti-phase.
// A/B discriminator: OccupancyPercent ~2x proves co-residency; if dur
// regresses WITH 2x occupancy, cross-WG overlap is dead (phase-lock).

#define GRIDN 28
#define BATCH 128
#define HID   64
#define NDIR  4
#define FC_HD 512
#define OUT_N 10
#define NTHR  512
#define NSLOT 29          // 28 frontier rows + permanent-zero row (r = -1)
#define S_H   104         // f16/slot: [0,64) h | [64]=x [65]=1 [66,96)=0 | 8 pad
#define S_C   68          // float/slot: 64 c + 4 pad

typedef _Float16 f16;
typedef _Float16 f16x8 __attribute__((ext_vector_type(8)));
typedef float    f32x4 __attribute__((ext_vector_type(4)));

#define LOG2E  1.44269504088896340736f
#define LOG2E2 2.88539008177792681472f

__device__ __forceinline__ float rcpf(float x) { return __builtin_amdgcn_rcpf(x); }
__device__ __forceinline__ float ex2(float x)  { return __builtin_amdgcn_exp2f(x); }

__global__ __launch_bounds__(NTHR)
void mdlstm_kernel(const float* __restrict__ x,    // [B][28][28]
                   const float* __restrict__ Wx,   // [4][320]
                   const float* __restrict__ U,    // [4][128][320]
                   const float* __restrict__ bias, // [4][320]
                   float* __restrict__ Hout)       // [4][B][64]
{
    const int d    = blockIdx.x & 3;
    const int tile = blockIdx.x >> 2;     // 0..127 = batch index
    const int tid  = threadIdx.x;
    const int lane = tid & 63;
    const int wave = tid >> 6;            // 0..7
    const int wm   = wave >> 2;           // M-tile parity 0/1
    const int wh   = wave & 3;            // h-subtile (n = wh*16 + l16)
    const int l16  = lane & 15;
    const int q    = lane >> 4;
    const int nb   = wh * 16 + l16;       // this lane's h index 0..63

    __shared__ __align__(16) f16 Fh[2][NSLOT * S_H];
    __shared__ float             Fc[2][NSLOT * S_C];
    __shared__ float             xs[GRIDN][GRIDN];

    for (int i = tid; i < 2 * NSLOT * S_H; i += NTHR) ((f16*)Fh)[i] = (f16)0.0f;
    for (int i = tid; i < 2 * NSLOT * S_C; i += NTHR) ((float*)Fc)[i] = 0.0f;
    for (int i = tid; i < GRIDN * GRIDN; i += NTHR) {
        int c = i % GRIDN, r = i / GRIDN;
        int rr = (d & 2) ? (GRIDN - 1 - r) : r;
        int cc = (d & 1) ? (GRIDN - 1 - c) : c;
        xs[r][c] = x[(tile * GRIDN + rr) * GRIDN + cc];
    }

    // ---- B-fragments in registers, gate-scaled: 25 x f16x8
    // sigmoid gates scaled by -log2e (sig = rcp(1+2^acc)); g gate by +2log2e.
    f16x8 bf[5][5];
#pragma unroll
    for (int g = 0; g < 5; ++g) {
        const float sc = (g == 4) ? LOG2E2 : -LOG2E;
        int n = g * 64 + nb;
#pragma unroll
        for (int ks = 0; ks < 4; ++ks) {
            f16x8 v;
            int kb = ks * 32 + q * 8;
#pragma unroll
            for (int j = 0; j < 8; ++j)
                v[j] = (f16)(sc * U[(d * 128 + kb + j) * 320 + n]);
            bf[g][ks] = v;
        }
        f16x8 v5 = {(f16)0, (f16)0, (f16)0, (f16)0, (f16)0, (f16)0, (f16)0, (f16)0};
        if (q == 0) {
            v5[0] = (f16)(sc * Wx[d * 320 + n]);
            v5[1] = (f16)(sc * bias[d * 320 + n]);
        }
        bf[g][4] = v5;
    }
    __syncthreads();   // zero-init complete

    // ones in the x-region ([65]=1) of every slot, both buffers; seed x(0,0)
    if (tid < 2 * NSLOT) {
        int buf = tid / NSLOT, sl = tid % NSLOT;
        Fh[buf][sl * S_H + 65] = (f16)1.0f;
    }
    if (tid == 0) Fh[0][27 * S_H + 64] = (f16)xs[0][0];
    __syncthreads();

    // stagger CU-sharing WGs (grid passes 0/1) toward anti-phase
    if (blockIdx.x & 256) { __builtin_amdgcn_s_sleep(16); }

    // one anti-diagonal; br is a literal at every callsite -> const-folds
    auto step = [&](int t, int br) __attribute__((always_inline)) {
        const int bw  = br ^ 1;
        const int rlo = (t > GRIDN - 1) ? (t - (GRIDN - 1)) : 0;
        const int rhi = (t < GRIDN - 1) ? t : (GRIDN - 1);
        const int k   = rhi - rlo + 1;
        const int nM  = (k + 15) >> 4;    // 1 or 2 tasks of 16 grid rows

        // stage x for diagonal t+1 into the write buffer (tail lanes)
        if (t < 2 * GRIDN - 2 && tid >= NTHR - GRIDN) {
            int j = tid - (NTHR - GRIDN);
            int rlo2 = (t + 1 > GRIDN - 1) ? (t + 1 - (GRIDN - 1)) : 0;
            int rhi2 = (t + 1 < GRIDN - 1) ? (t + 1) : (GRIDN - 1);
            if (j <= rhi2 - rlo2) {
                int r = rlo2 + j;
                Fh[bw][(27 - r) * S_H + 64] = (f16)xs[r][t + 1 - r];
            }
        }

        // each wave: at most ONE task (nM <= 2, split by wm parity)
        if (wm < nM) {
            const int mt = wm;
            // ---- A fragments: task row mA = grid row (clamped)
            int mA = mt * 16 + l16;
            int jA = mA > k - 1 ? k - 1 : mA;
            int slA = 27 - (rlo + jA);
            const f16* ab = &Fh[br][slA * S_H];
            f16x8 a0 = *(const f16x8*)(ab + q * 8);              // h_left k 0..63
            f16x8 a1 = *(const f16x8*)(ab + 32 + q * 8);
            f16x8 a2 = *(const f16x8*)(ab + S_H + q * 8);        // h_up   k 64..127
            f16x8 a3 = *(const f16x8*)(ab + S_H + 32 + q * 8);
            f16x8 a4 = *(const f16x8*)(ab + 64 + q * 8);         // {x,1,0..} k 128..159

            // ---- epilogue addresses + c-state PRELOAD (LDS latency drains
            // under the MFMA block). C-row = q*4+i -> grid row mt*16+q*4+i.
            int j0 = mt * 16 + q * 4;
            int sl[4];
            const float* rp[4];
            float pcl[4], pcu[4];
#pragma unroll
            for (int i = 0; i < 4; ++i) {
                int jj = (j0 + i > k - 1) ? k - 1 : j0 + i;
                sl[i] = 27 - (rlo + jj);
                rp[i] = &Fc[br][sl[i] * S_C + nb];
                pcl[i] = rp[i][0];
                pcu[i] = rp[i][S_C];
            }

            const f32x4 z4 = {0.f, 0.f, 0.f, 0.f};               // shared zero-C
            f32x4 acc[5];
#pragma unroll
            for (int g = 0; g < 5; ++g) acc[g] = __builtin_amdgcn_mfma_f32_16x16x32_f16(a4, bf[g][4], z4, 0, 0, 0);
#pragma unroll
            for (int g = 0; g < 5; ++g) acc[g] = __builtin_amdgcn_mfma_f32_16x16x32_f16(a0, bf[g][0], acc[g], 0, 0, 0);
#pragma unroll
            for (int g = 0; g < 5; ++g) acc[g] = __builtin_amdgcn_mfma_f32_16x16x32_f16(a1, bf[g][1], acc[g], 0, 0, 0);
#pragma unroll
            for (int g = 0; g < 5; ++g) acc[g] = __builtin_amdgcn_mfma_f32_16x16x32_f16(a2, bf[g][2], acc[g], 0, 0, 0);
#pragma unroll
            for (int g = 0; g < 5; ++g) acc[g] = __builtin_amdgcn_mfma_f32_16x16x32_f16(a3, bf[g][3], acc[g], 0, 0, 0);

            // ---- gates + state, BRANCHLESS, trans-merged (R12 math):
            //   sig(i)*tanh(g)        = (tb-2)*rcp(ta*tb)
            //   sig(f1)*cl+sig(f2)*cu = (cl*tq+cu*tp)*rcp(tp*tq)
            //   sig(o)*tanh(cn)       = (te-2)*rcp(td*te), cn clamped to 22
            //     for te only (tanh(22)==1.0f exactly; prevents inf*0=NaN).
            // Clamped dummy rows duplicate row k-1's values -> benign
            // same-value same-address LDS writes (as in R12).
            const int DC = (bw - br) * (NSLOT * S_C);   // compile-time
            f16* whw = &Fh[bw][0];
#pragma unroll
            for (int i = 0; i < 4; ++i) {
                float ta = 1.0f + ex2(acc[0][i]);
                float tp = 1.0f + ex2(acc[1][i]);
                float tq = 1.0f + ex2(acc[2][i]);
                float td = 1.0f + ex2(acc[3][i]);
                float tb = 1.0f + ex2(acc[4][i]);
                float cn = (tb - 2.0f) * rcpf(ta * tb)
                         + (pcl[i] * tq + pcu[i] * tp) * rcpf(tp * tq);
                float cnc = fminf(cn, 22.0f);
                float te = 1.0f + ex2(LOG2E2 * cnc);
                float hn = (te - 2.0f) * rcpf(td * te);
                *(float*)(rp[i] + DC) = cn;
                whw[sl[i] * S_H + nb] = (f16)hn;
            }
        }
        __syncthreads();
    };

    for (int tb = 0; tb < 27; ++tb) { step(2 * tb, 0); step(2 * tb + 1, 1); }
    step(54, 0);

    // final h(27,27): t=54 wrote buf 1, slot 0
    if (tid < HID)
        Hout[(d * BATCH + tile) * HID + tid] = (float)Fh[1][tid];
}

// FC head (R18): one WG of 1024 threads per batch row (16 waves/WG,
// 128 WGs -> 8 waves/CU on 128 CUs). z1: 1 col/thread, K split in half
// (128-deep load chain); halves combine via LDS. z2/softmax as before.
__global__ __launch_bounds__(1024)
void fc_kernel(const float* __restrict__ Hin,  // [4][B][64]
               const float* __restrict__ W1, const float* __restrict__ b1,
               const float* __restrict__ W2, const float* __restrict__ b2,
               float* __restrict__ out)        // [B][10]
{
    const int b   = blockIdx.x;
    const int tid = threadIdx.x;
    __shared__ float hrow[NDIR * HID];
    __shared__ float psum[2][FC_HD];
    __shared__ float z1[FC_HD];
    __shared__ float ps[32][16];
    __shared__ float z2[16];

    if (tid < NDIR * HID)
        hrow[tid] = Hin[(tid >> 6) * (BATCH * HID) + b * HID + (tid & 63)];
    __syncthreads();

    {
        int col = tid & (FC_HD - 1);
        int hf  = tid >> 9;
        int f0  = hf * 128;
        float s = 0.0f;
#pragma unroll 16
        for (int f = 0; f < 128; ++f)
            s += hrow[f0 + f] * W1[(f0 + f) * FC_HD + col];
        psum[hf][col] = s;
    }
    __syncthreads();

    if (tid < FC_HD)
        z1[tid] = fmaxf(psum[0][tid] + psum[1][tid] + b1[tid], 0.0f);
    __syncthreads();

    if (tid < 512) {
        int j = tid & 15, sl = tid >> 4;
        float s = 0.0f;
        if (j < OUT_N) {
#pragma unroll
            for (int i = 0; i < 16; ++i) {
                int kk = sl * 16 + i;
                s += z1[kk] * W2[kk * OUT_N + j];
            }
        }
        ps[sl][j] = s;
    }
    __syncthreads();

    if (tid < OUT_N) {
        float s = b2[tid];
#pragma unroll
        for (int sl = 0; sl < 32; ++sl) s += ps[sl][tid];
        z2[tid] = s;
    }
    __syncthreads();

    if (tid == 0) {
        float m = z2[0];
        for (int j = 1; j < OUT_N; ++j) m = fmaxf(m, z2[j]);
        float sum = 0.0f, e[OUT_N];
        for (int j = 0; j < OUT_N; ++j) { e[j] = __expf(z2[j] - m); sum += e[j]; }
        float inv = 1.0f / sum;
        for (int j = 0; j < OUT_N; ++j) out[b * OUT_N + j] = e[j] * inv;
    }
}

extern "C" void kernel_launch(void* const* d_in, const int* in_sizes, int n_in,
                              void* d_out, int out_size, void* d_ws, size_t ws_size,
                              hipStream_t stream) {
    const float* x  = (const float*)d_in[0];
    const float* Wx = (const float*)d_in[1];
    const float* U  = (const float*)d_in[2];
    const float* bs = (const float*)d_in[3];
    const float* W1 = (const float*)d_in[4];
    const float* b1 = (const float*)d_in[5];
    const float* W2 = (const float*)d_in[6];
    const float* b2 = (const float*)d_in[7];
    float* out = (float*)d_out;
    float* Hws = (float*)d_ws;   // [4][128][64] fp32 = 128 KiB

    mdlstm_kernel<<<NDIR * BATCH, NTHR, 0, stream>>>(x, Wx, U, bs, Hws);
    fc_kernel<<<BATCH, 1024, 0, stream>>>(Hws, W1, b1, W2, b2, out);
}

// Round 5
// 167.088 us; speedup vs baseline: 1.0749x; 1.0749x over previous
//
#include <hip/hip_runtime.h>
#include <hip/hip_bf16.h>

// 2D-MDLSTM (4 directions) + FC head for MI355X — round 20.
//
// R19 post-mortem: OccupancyPercent stayed ~22 (not 2x) with LDS 31KB ->
// co-residency was REGISTER-blocked, not LDS-blocked: VGPR_Count 92 excludes
// AGPRs (bf[5][5]=100 AGPRs); ~220 unified regs/wave caps at 2 waves/SIMD =
// 8 waves/CU. An 8-wave WG fills the CU exactly; the 512 WGs ran as ~2
// serialized passes (118 ~= 2x59 us). Side-finding: per-step fixed latency
// ~1470 cyc + marginal work ~2200 cyc (R12 3670 @ full work vs R19 2570 @
// half work) — phase-serialization theory confirmed, mechanism was wrong.
//
// R20: co-residency at CONSTANT wave count. WG = 256 thr (4 waves, wh only),
// BT=1, grid = 512 -> 2 WGs/CU: same 8 waves/CU and per-SIMD register
// pressure as R12 (proven to fit), 2x31KB = 62KB LDS, but TWO independent
// barrier groups per CU -> WG-A's trans/epilogue overlaps WG-B's LDS/MFMA
// burst (m114 MFMA||VALU overlap, applied across WGs).
// Critical-path check: per-wave serial tasks/step = ceil(k/16), sum = 78 =
// exactly R12's sum(ceil(nM/2)) at every k. Identical critical count; no
// idle wm-half (R19 wasted one on 32/55 steps); 4-wave barriers (less
// skew); back-to-back mt tasks give in-wave ILP. Cost: +26% aggregate
// padding on <50%-busy pipes; 2x prologue per CU (overlapped).
// Discriminator: same counters as R12 + dur ~84-92 => phase-lock => this
// family is closed (latency floor = roofline for the structure).

#define GRIDN 28
#define BATCH 128
#define HID   64
#define NDIR  4
#define FC_HD 512
#define OUT_N 10
#define NTHR  256
#define NSLOT 29          // 28 frontier rows + permanent-zero row (r = -1)
#define S_H   104         // f16/slot: [0,64) h | [64]=x [65]=1 [66,96)=0 | 8 pad
#define S_C   68          // float/slot: 64 c + 4 pad

typedef _Float16 f16;
typedef _Float16 f16x8 __attribute__((ext_vector_type(8)));
typedef float    f32x4 __attribute__((ext_vector_type(4)));

#define LOG2E  1.44269504088896340736f
#define LOG2E2 2.88539008177792681472f

__device__ __forceinline__ float rcpf(float x) { return __builtin_amdgcn_rcpf(x); }
__device__ __forceinline__ float ex2(float x)  { return __builtin_amdgcn_exp2f(x); }

__global__ __launch_bounds__(NTHR)
void mdlstm_kernel(const float* __restrict__ x,    // [B][28][28]
                   const float* __restrict__ Wx,   // [4][320]
                   const float* __restrict__ U,    // [4][128][320]
                   const float* __restrict__ bias, // [4][320]
                   float* __restrict__ Hout)       // [4][B][64]
{
    const int d    = blockIdx.x & 3;
    const int tile = blockIdx.x >> 2;     // 0..127 = batch index
    const int tid  = threadIdx.x;
    const int lane = tid & 63;
    const int wh   = tid >> 6;            // wave 0..3 = h-subtile
    const int l16  = lane & 15;
    const int q    = lane >> 4;
    const int nb   = wh * 16 + l16;       // this lane's h index 0..63

    __shared__ __align__(16) f16 Fh[2][NSLOT * S_H];
    __shared__ float             Fc[2][NSLOT * S_C];
    __shared__ float             xs[GRIDN][GRIDN];

    for (int i = tid; i < 2 * NSLOT * S_H; i += NTHR) ((f16*)Fh)[i] = (f16)0.0f;
    for (int i = tid; i < 2 * NSLOT * S_C; i += NTHR) ((float*)Fc)[i] = 0.0f;
    for (int i = tid; i < GRIDN * GRIDN; i += NTHR) {
        int c = i % GRIDN, r = i / GRIDN;
        int rr = (d & 2) ? (GRIDN - 1 - r) : r;
        int cc = (d & 1) ? (GRIDN - 1 - c) : c;
        xs[r][c] = x[(tile * GRIDN + rr) * GRIDN + cc];
    }

    // ---- B-fragments in registers, gate-scaled: 25 x f16x8
    // sigmoid gates scaled by -log2e (sig = rcp(1+2^acc)); g gate by +2log2e.
    f16x8 bf[5][5];
#pragma unroll
    for (int g = 0; g < 5; ++g) {
        const float sc = (g == 4) ? LOG2E2 : -LOG2E;
        int n = g * 64 + nb;
#pragma unroll
        for (int ks = 0; ks < 4; ++ks) {
            f16x8 v;
            int kb = ks * 32 + q * 8;
#pragma unroll
            for (int j = 0; j < 8; ++j)
                v[j] = (f16)(sc * U[(d * 128 + kb + j) * 320 + n]);
            bf[g][ks] = v;
        }
        f16x8 v5 = {(f16)0, (f16)0, (f16)0, (f16)0, (f16)0, (f16)0, (f16)0, (f16)0};
        if (q == 0) {
            v5[0] = (f16)(sc * Wx[d * 320 + n]);
            v5[1] = (f16)(sc * bias[d * 320 + n]);
        }
        bf[g][4] = v5;
    }
    __syncthreads();   // zero-init complete

    // ones in the x-region ([65]=1) of every slot, both buffers; seed x(0,0)
    if (tid < 2 * NSLOT) {
        int buf = tid / NSLOT, sl = tid % NSLOT;
        Fh[buf][sl * S_H + 65] = (f16)1.0f;
    }
    if (tid == 0) Fh[0][27 * S_H + 64] = (f16)xs[0][0];
    __syncthreads();

    // stagger CU-sharing WGs (blockIdx i and i+256 typically share a CU)
    // toward anti-phase
    if (blockIdx.x & 256) { __builtin_amdgcn_s_sleep(8); }

    // one anti-diagonal; br is a literal at every callsite -> const-folds
    auto step = [&](int t, int br) __attribute__((always_inline)) {
        const int bw  = br ^ 1;
        const int rlo = (t > GRIDN - 1) ? (t - (GRIDN - 1)) : 0;
        const int rhi = (t < GRIDN - 1) ? t : (GRIDN - 1);
        const int k   = rhi - rlo + 1;
        const int nM  = (k + 15) >> 4;    // 1 or 2 tasks of 16 grid rows

        // stage x for diagonal t+1 into the write buffer (tail lanes)
        if (t < 2 * GRIDN - 2 && tid >= NTHR - GRIDN) {
            int j = tid - (NTHR - GRIDN);
            int rlo2 = (t + 1 > GRIDN - 1) ? (t + 1 - (GRIDN - 1)) : 0;
            int rhi2 = (t + 1 < GRIDN - 1) ? (t + 1) : (GRIDN - 1);
            if (j <= rhi2 - rlo2) {
                int r = rlo2 + j;
                Fh[bw][(27 - r) * S_H + 64] = (f16)xs[r][t + 1 - r];
            }
        }

        // each wave handles all nM tasks serially (nM <= 2); back-to-back
        // tasks provide in-wave ILP (second task's ds_reads issue under the
        // first task's MFMAs)
        for (int mt = 0; mt < nM; ++mt) {
            // ---- A fragments: task row mA = grid row (clamped)
            int mA = mt * 16 + l16;
            int jA = mA > k - 1 ? k - 1 : mA;
            int slA = 27 - (rlo + jA);
            const f16* ab = &Fh[br][slA * S_H];
            f16x8 a0 = *(const f16x8*)(ab + q * 8);              // h_left k 0..63
            f16x8 a1 = *(const f16x8*)(ab + 32 + q * 8);
            f16x8 a2 = *(const f16x8*)(ab + S_H + q * 8);        // h_up   k 64..127
            f16x8 a3 = *(const f16x8*)(ab + S_H + 32 + q * 8);
            f16x8 a4 = *(const f16x8*)(ab + 64 + q * 8);         // {x,1,0..} k 128..159

            // ---- epilogue addresses + c-state PRELOAD (LDS latency drains
            // under the MFMA block). C-row = q*4+i -> grid row mt*16+q*4+i.
            int j0 = mt * 16 + q * 4;
            int sl[4];
            const float* rp[4];
            float pcl[4], pcu[4];
#pragma unroll
            for (int i = 0; i < 4; ++i) {
                int jj = (j0 + i > k - 1) ? k - 1 : j0 + i;
                sl[i] = 27 - (rlo + jj);
                rp[i] = &Fc[br][sl[i] * S_C + nb];
                pcl[i] = rp[i][0];
                pcu[i] = rp[i][S_C];
            }

            const f32x4 z4 = {0.f, 0.f, 0.f, 0.f};               // shared zero-C
            f32x4 acc[5];
#pragma unroll
            for (int g = 0; g < 5; ++g) acc[g] = __builtin_amdgcn_mfma_f32_16x16x32_f16(a4, bf[g][4], z4, 0, 0, 0);
#pragma unroll
            for (int g = 0; g < 5; ++g) acc[g] = __builtin_amdgcn_mfma_f32_16x16x32_f16(a0, bf[g][0], acc[g], 0, 0, 0);
#pragma unroll
            for (int g = 0; g < 5; ++g) acc[g] = __builtin_amdgcn_mfma_f32_16x16x32_f16(a1, bf[g][1], acc[g], 0, 0, 0);
#pragma unroll
            for (int g = 0; g < 5; ++g) acc[g] = __builtin_amdgcn_mfma_f32_16x16x32_f16(a2, bf[g][2], acc[g], 0, 0, 0);
#pragma unroll
            for (int g = 0; g < 5; ++g) acc[g] = __builtin_amdgcn_mfma_f32_16x16x32_f16(a3, bf[g][3], acc[g], 0, 0, 0);

            // ---- gates + state, BRANCHLESS, trans-merged (R12 math):
            //   sig(i)*tanh(g)        = (tb-2)*rcp(ta*tb)
            //   sig(f1)*cl+sig(f2)*cu = (cl*tq+cu*tp)*rcp(tp*tq)
            //   sig(o)*tanh(cn)       = (te-2)*rcp(td*te), cn clamped to 22
            //     for te only (tanh(22)==1.0f exactly; prevents inf*0=NaN).
            // Clamped dummy rows duplicate row k-1's values -> benign
            // same-value same-address LDS writes (as in R12).
            const int DC = (bw - br) * (NSLOT * S_C);   // compile-time
            f16* whw = &Fh[bw][0];
#pragma unroll
            for (int i = 0; i < 4; ++i) {
                float ta = 1.0f + ex2(acc[0][i]);
                float tp = 1.0f + ex2(acc[1][i]);
                float tq = 1.0f + ex2(acc[2][i]);
                float td = 1.0f + ex2(acc[3][i]);
                float tb = 1.0f + ex2(acc[4][i]);
                float cn = (tb - 2.0f) * rcpf(ta * tb)
                         + (pcl[i] * tq + pcu[i] * tp) * rcpf(tp * tq);
                float cnc = fminf(cn, 22.0f);
                float te = 1.0f + ex2(LOG2E2 * cnc);
                float hn = (te - 2.0f) * rcpf(td * te);
                *(float*)(rp[i] + DC) = cn;
                whw[sl[i] * S_H + nb] = (f16)hn;
            }
        }
        __syncthreads();
    };

    for (int tb = 0; tb < 27; ++tb) { step(2 * tb, 0); step(2 * tb + 1, 1); }
    step(54, 0);

    // final h(27,27): t=54 wrote buf 1, slot 0
    if (tid < HID)
        Hout[(d * BATCH + tile) * HID + tid] = (float)Fh[1][tid];
}

// FC head (R18): one WG of 1024 threads per batch row (16 waves/WG,
// 128 WGs -> 8 waves/CU on 128 CUs). z1: 1 col/thread, K split in half
// (128-deep load chain); halves combine via LDS. z2/softmax as before.
__global__ __launch_bounds__(1024)
void fc_kernel(const float* __restrict__ Hin,  // [4][B][64]
               const float* __restrict__ W1, const float* __restrict__ b1,
               const float* __restrict__ W2, const float* __restrict__ b2,
               float* __restrict__ out)        // [B][10]
{
    const int b   = blockIdx.x;
    const int tid = threadIdx.x;
    __shared__ float hrow[NDIR * HID];
    __shared__ float psum[2][FC_HD];
    __shared__ float z1[FC_HD];
    __shared__ float ps[32][16];
    __shared__ float z2[16];

    if (tid < NDIR * HID)
        hrow[tid] = Hin[(tid >> 6) * (BATCH * HID) + b * HID + (tid & 63)];
    __syncthreads();

    {
        int col = tid & (FC_HD - 1);
        int hf  = tid >> 9;
        int f0  = hf * 128;
        float s = 0.0f;
#pragma unroll 16
        for (int f = 0; f < 128; ++f)
            s += hrow[f0 + f] * W1[(f0 + f) * FC_HD + col];
        psum[hf][col] = s;
    }
    __syncthreads();

    if (tid < FC_HD)
        z1[tid] = fmaxf(psum[0][tid] + psum[1][tid] + b1[tid], 0.0f);
    __syncthreads();

    if (tid < 512) {
        int j = tid & 15, sl = tid >> 4;
        float s = 0.0f;
        if (j < OUT_N) {
#pragma unroll
            for (int i = 0; i < 16; ++i) {
                int kk = sl * 16 + i;
                s += z1[kk] * W2[kk * OUT_N + j];
            }
        }
        ps[sl][j] = s;
    }
    __syncthreads();

    if (tid < OUT_N) {
        float s = b2[tid];
#pragma unroll
        for (int sl = 0; sl < 32; ++sl) s += ps[sl][tid];
        z2[tid] = s;
    }
    __syncthreads();

    if (tid == 0) {
        float m = z2[0];
        for (int j = 1; j < OUT_N; ++j) m = fmaxf(m, z2[j]);
        float sum = 0.0f, e[OUT_N];
        for (int j = 0; j < OUT_N; ++j) { e[j] = __expf(z2[j] - m); sum += e[j]; }
        float inv = 1.0f / sum;
        for (int j = 0; j < OUT_N; ++j) out[b * OUT_N + j] = e[j] * inv;
    }
}

extern "C" void kernel_launch(void* const* d_in, const int* in_sizes, int n_in,
                              void* d_out, int out_size, void* d_ws, size_t ws_size,
                              hipStream_t stream) {
    const float* x  = (const float*)d_in[0];
    const float* Wx = (const float*)d_in[1];
    const float* U  = (const float*)d_in[2];
    const float* bs = (const float*)d_in[3];
    const float* W1 = (const float*)d_in[4];
    const float* b1 = (const float*)d_in[5];
    const float* W2 = (const float*)d_in[6];
    const float* b2 = (const float*)d_in[7];
    float* out = (float*)d_out;
    float* Hws = (float*)d_ws;   // [4][128][64] fp32 = 128 KiB

    mdlstm_kernel<<<NDIR * BATCH, NTHR, 0, stream>>>(x, Wx, U, bs, Hws);
    fc_kernel<<<BATCH, 1024, 0, stream>>>(Hws, W1, b1, W2, b2, out);
}

// Round 6
// 150.621 us; speedup vs baseline: 1.1924x; 1.1093x over previous
//
#include <hip/hip_runtime.h>
#include <hip/hip_bf16.h>

// 2D-MDLSTM (4 directions) + FC head for MI355X — round 21.
//
// R20 post-mortem: 2 co-resident 4-wave WGs/CU REGRESSED (105 us): VALU work
// 105x60% = 63 us-equiv vs R12's 84x53% = 45 — the +30% BT=1 padding + 2x
// prologue showed up ~fully in time. Pipe work adds LINEARLY across
// co-resident WGs; no cross-WG phase overlap exists. Decorrelation family
// closed (R19 occupancy-blocked, R20 co-resident-but-linear). Model:
// wall = fixed ~1470 cyc/step latency + aggregate pipe work. Only lever
// left: reduce aggregate work in the R12 structure (minimal padding, 78
// critical tasks — proven optimal layout).
//
// R21 = R12 + clean a4-elimination (R16's idea WITHOUT its two killers —
// absolute mapping and global-x):
//   - 5th MFMA K-step (x*Wx+b via mostly-zero a4 row) replaced by C-init
//     acc[g] = sc*(x*Wx+b): 20 VALU FMAs/task. MFMA/task 25->20 (-20%).
//   - x read DIRECTLY from LDS-resident xs[] (4 reads, uniform within each
//     q-group -> LDS broadcast, conflict-free), preloaded with pcl/pcu so
//     latency drains under the MFMA block. f32 path (more precise than the
//     old f16 Fh-staging).
//   - Deleted: a4 b128 read (1 of 5 A-reads), per-step tail-lane x-staging
//     (wave-7 divergence + LDS writes), ones-seeding, 20 of 100 bf AGPRs.
// Everything else is R12 verbatim (BT=2, 256 WGs x 512 thr, wm/wh split,
// S_H=104/S_C=68, double-buffered frontier, merged transcendentals with
// cn<=22 clamp, t-loop x2 unrolled).
// Discriminator: if mdlstm >= 84 us despite -20% MFMA & -20% LDS work, the
// step is latency-floor-bound -> structure roofline.

#define GRIDN 28
#define BATCH 128
#define HID   64
#define NDIR  4
#define FC_HD 512
#define OUT_N 10
#define BT    2
#define NTHR  512
#define NSLOT 29          // 28 frontier rows + permanent-zero row (r = -1)
#define S_H   104         // f16/slot: [0,64) h | rest unused pad (bank stagger)
#define S_C   68          // float/slot: 64 c + 4 pad

typedef _Float16 f16;
typedef _Float16 f16x8 __attribute__((ext_vector_type(8)));
typedef float    f32x4 __attribute__((ext_vector_type(4)));

#define LOG2E  1.44269504088896340736f
#define LOG2E2 2.88539008177792681472f

__device__ __forceinline__ float rcpf(float x) { return __builtin_amdgcn_rcpf(x); }
__device__ __forceinline__ float ex2(float x)  { return __builtin_amdgcn_exp2f(x); }

__global__ __launch_bounds__(NTHR)
void mdlstm_kernel(const float* __restrict__ x,    // [B][28][28]
                   const float* __restrict__ Wx,   // [4][320]
                   const float* __restrict__ U,    // [4][128][320]
                   const float* __restrict__ bias, // [4][320]
                   float* __restrict__ Hout)       // [4][B][64]
{
    const int d    = blockIdx.x & 3;
    const int tile = blockIdx.x >> 2;     // 0..63 batch-pair
    const int tid  = threadIdx.x;
    const int lane = tid & 63;
    const int wave = tid >> 6;            // 0..7
    const int wm   = wave >> 2;           // M-tile parity 0/1
    const int wh   = wave & 3;            // h-subtile (n = wh*16 + l16)
    const int l16  = lane & 15;
    const int q    = lane >> 4;
    const int nb   = wh * 16 + l16;       // this lane's h index 0..63

    __shared__ __align__(16) f16 Fh[2][BT][NSLOT * S_H];
    __shared__ float             Fc[2][BT][NSLOT * S_C];
    __shared__ float             xs[GRIDN][GRIDN][BT];

    for (int i = tid; i < 2 * BT * NSLOT * S_H; i += NTHR) ((f16*)Fh)[i] = (f16)0.0f;
    for (int i = tid; i < 2 * BT * NSLOT * S_C; i += NTHR) ((float*)Fc)[i] = 0.0f;
    for (int i = tid; i < GRIDN * GRIDN * BT; i += NTHR) {
        int bl = i & 1, rc = i >> 1, c = rc % GRIDN, r = rc / GRIDN;
        int rr = (d & 2) ? (GRIDN - 1 - r) : r;
        int cc = (d & 1) ? (GRIDN - 1 - c) : c;
        xs[r][c][bl] = x[((tile * BT + bl) * GRIDN + rr) * GRIDN + cc];
    }

    // ---- B-fragments in registers, gate-scaled: 20 x f16x8 (80 regs)
    // sigmoid gates scaled by -log2e (sig = rcp(1+2^acc)); g gate by +2log2e.
    // x*Wx + b folded into the MFMA C-initializer (sWx/sB per lane-column).
    f16x8 bf[5][4];
    float sWx[5], sB[5];
#pragma unroll
    for (int g = 0; g < 5; ++g) {
        const float sc = (g == 4) ? LOG2E2 : -LOG2E;
        int n = g * 64 + nb;
#pragma unroll
        for (int ks = 0; ks < 4; ++ks) {
            f16x8 v;
            int kb = ks * 32 + q * 8;
#pragma unroll
            for (int j = 0; j < 8; ++j)
                v[j] = (f16)(sc * U[(d * 128 + kb + j) * 320 + n]);
            bf[g][ks] = v;
        }
        sWx[g] = sc * Wx[d * 320 + n];
        sB[g]  = sc * bias[d * 320 + n];
    }
    __syncthreads();   // zero-init + xs staging complete

    // one anti-diagonal; br is a literal at every callsite -> const-folds
    auto step = [&](int t, int br) __attribute__((always_inline)) {
        const int bw  = br ^ 1;
        const int rlo = (t > GRIDN - 1) ? (t - (GRIDN - 1)) : 0;
        const int rhi = (t < GRIDN - 1) ? t : (GRIDN - 1);
        const int k   = rhi - rlo + 1;
        const int nM  = (2 * k + 15) >> 4;

        for (int mt = wm; mt < nM; mt += 2) {
            // ---- A fragments: task row mA -> (batch bA, grid row rA)
            int mA = mt * 16 + l16;
            int jA = mA >> 1; if (jA > k - 1) jA = k - 1;
            int bA = mA & 1;
            int slA = 27 - (rlo + jA);
            const f16* ab = &Fh[br][bA][slA * S_H];
            f16x8 a0 = *(const f16x8*)(ab + q * 8);              // h_left k 0..31
            f16x8 a1 = *(const f16x8*)(ab + 32 + q * 8);         // h_left k 32..63
            f16x8 a2 = *(const f16x8*)(ab + S_H + q * 8);        // h_up   k 0..31
            f16x8 a3 = *(const f16x8*)(ab + S_H + 32 + q * 8);   // h_up   k 32..63

            // ---- epilogue addresses + c-state + x PRELOAD (before MFMAs:
            // their ~120 cyc LDS latency drains under the MFMA block).
            // x reads are q-group-uniform -> LDS broadcast, conflict-free.
            int j0  = mt * 8 + q * 2;
            int jj0 = (j0     > k - 1) ? k - 1 : j0;
            int jj1 = (j0 + 1 > k - 1) ? k - 1 : j0 + 1;
            int sl0 = 27 - (rlo + jj0);
            int sl1 = 27 - (rlo + jj1);
            int r0  = rlo + jj0, r1 = rlo + jj1;
            int c0  = t - r0,    c1 = t - r1;       // in [0,27] by construction
            const float* rp[4] = { &Fc[br][0][sl0 * S_C + nb], &Fc[br][1][sl0 * S_C + nb],
                                   &Fc[br][0][sl1 * S_C + nb], &Fc[br][1][sl1 * S_C + nb] };
            float pcl[4], pcu[4];
#pragma unroll
            for (int i = 0; i < 4; ++i) { pcl[i] = rp[i][0]; pcu[i] = rp[i][S_C]; }
            float xv[4] = { xs[r0][c0][0], xs[r0][c0][1],
                            xs[r1][c1][0], xs[r1][c1][1] };

            // ---- C-init = sc*(x*Wx + b), then 4-step MFMA chain per gate
            f32x4 acc[5];
#pragma unroll
            for (int g = 0; g < 5; ++g) {
                f32x4 ci;
#pragma unroll
                for (int i = 0; i < 4; ++i) ci[i] = sB[g] + sWx[g] * xv[i];
                acc[g] = ci;
            }
#pragma unroll
            for (int g = 0; g < 5; ++g) acc[g] = __builtin_amdgcn_mfma_f32_16x16x32_f16(a0, bf[g][0], acc[g], 0, 0, 0);
#pragma unroll
            for (int g = 0; g < 5; ++g) acc[g] = __builtin_amdgcn_mfma_f32_16x16x32_f16(a1, bf[g][1], acc[g], 0, 0, 0);
#pragma unroll
            for (int g = 0; g < 5; ++g) acc[g] = __builtin_amdgcn_mfma_f32_16x16x32_f16(a2, bf[g][2], acc[g], 0, 0, 0);
#pragma unroll
            for (int g = 0; g < 5; ++g) acc[g] = __builtin_amdgcn_mfma_f32_16x16x32_f16(a3, bf[g][3], acc[g], 0, 0, 0);

            // ---- gates + state, BRANCHLESS, trans-merged.
            // acc0=-log2e*i  acc1=-log2e*f1  acc2=-log2e*f2  acc3=-log2e*o
            // acc4=+2log2e*g
            //   sig(i)*tanh(g)        = (tb-2)*rcp(ta*tb)
            //   sig(f1)*cl+sig(f2)*cu = (cl*tq+cu*tp)*rcp(tp*tq)
            //   sig(o)*tanh(cn)       = (te-2)*rcp(td*te), cn clamped to 22
            //     for te only (tanh(22)==1.0f exactly; prevents te=inf ->
            //     inf*0=NaN when the accumulated c exceeds 44 — the R11 bug).
            // Clamped dummy rows duplicate row k-1's values -> benign
            // same-value same-address LDS writes (as in R12).
            const int DC = (bw - br) * (BT * NSLOT * S_C);   // compile-time
            int ih0 = sl0 * S_H + nb, ih1 = sl1 * S_H + nb;
            f16* wh0 = &Fh[bw][0][0];
            f16* wh1 = &Fh[bw][1][0];
#pragma unroll
            for (int i = 0; i < 4; ++i) {
                float ta = 1.0f + ex2(acc[0][i]);
                float tp = 1.0f + ex2(acc[1][i]);
                float tq = 1.0f + ex2(acc[2][i]);
                float td = 1.0f + ex2(acc[3][i]);
                float tb = 1.0f + ex2(acc[4][i]);
                float cn = (tb - 2.0f) * rcpf(ta * tb)
                         + (pcl[i] * tq + pcu[i] * tp) * rcpf(tp * tq);
                float cnc = fminf(cn, 22.0f);
                float te = 1.0f + ex2(LOG2E2 * cnc);
                float hn = (te - 2.0f) * rcpf(td * te);
                *(float*)(rp[i] + DC) = cn;
                ((i & 1) ? wh1 : wh0)[(i < 2) ? ih0 : ih1] = (f16)hn;
            }
        }
        __syncthreads();
    };

    for (int tb = 0; tb < 27; ++tb) { step(2 * tb, 0); step(2 * tb + 1, 1); }
    step(54, 0);

    // final h(27,27): t=54 wrote buf 1, slot 0
    if (tid < BT * HID) {
        int bl = tid >> 6, h = tid & 63;
        Hout[(d * BATCH + tile * BT + bl) * HID + h] = (float)Fh[1][bl][h];
    }
}

// FC head (R18): one WG of 1024 threads per batch row (16 waves/WG,
// 128 WGs -> 8 waves/CU on 128 CUs). z1: 1 col/thread, K split in half
// (128-deep load chain); halves combine via LDS. z2/softmax as before.
__global__ __launch_bounds__(1024)
void fc_kernel(const float* __restrict__ Hin,  // [4][B][64]
               const float* __restrict__ W1, const float* __restrict__ b1,
               const float* __restrict__ W2, const float* __restrict__ b2,
               float* __restrict__ out)        // [B][10]
{
    const int b   = blockIdx.x;
    const int tid = threadIdx.x;
    __shared__ float hrow[NDIR * HID];
    __shared__ float psum[2][FC_HD];
    __shared__ float z1[FC_HD];
    __shared__ float ps[32][16];
    __shared__ float z2[16];

    if (tid < NDIR * HID)
        hrow[tid] = Hin[(tid >> 6) * (BATCH * HID) + b * HID + (tid & 63)];
    __syncthreads();

    {
        int col = tid & (FC_HD - 1);
        int hf  = tid >> 9;
        int f0  = hf * 128;
        float s = 0.0f;
#pragma unroll 16
        for (int f = 0; f < 128; ++f)
            s += hrow[f0 + f] * W1[(f0 + f) * FC_HD + col];
        psum[hf][col] = s;
    }
    __syncthreads();

    if (tid < FC_HD)
        z1[tid] = fmaxf(psum[0][tid] + psum[1][tid] + b1[tid], 0.0f);
    __syncthreads();

    if (tid < 512) {
        int j = tid & 15, sl = tid >> 4;
        float s = 0.0f;
        if (j < OUT_N) {
#pragma unroll
            for (int i = 0; i < 16; ++i) {
                int kk = sl * 16 + i;
                s += z1[kk] * W2[kk * OUT_N + j];
            }
        }
        ps[sl][j] = s;
    }
    __syncthreads();

    if (tid < OUT_N) {
        float s = b2[tid];
#pragma unroll
        for (int sl = 0; sl < 32; ++sl) s += ps[sl][tid];
        z2[tid] = s;
    }
    __syncthreads();

    if (tid == 0) {
        float m = z2[0];
        for (int j = 1; j < OUT_N; ++j) m = fmaxf(m, z2[j]);
        float sum = 0.0f, e[OUT_N];
        for (int j = 0; j < OUT_N; ++j) { e[j] = __expf(z2[j] - m); sum += e[j]; }
        float inv = 1.0f / sum;
        for (int j = 0; j < OUT_N; ++j) out[b * OUT_N + j] = e[j] * inv;
    }
}

extern "C" void kernel_launch(void* const* d_in, const int* in_sizes, int n_in,
                              void* d_out, int out_size, void* d_ws, size_t ws_size,
                              hipStream_t stream) {
    const float* x  = (const float*)d_in[0];
    const float* Wx = (const float*)d_in[1];
    const float* U  = (const float*)d_in[2];
    const float* bs = (const float*)d_in[3];
    const float* W1 = (const float*)d_in[4];
    const float* b1 = (const float*)d_in[5];
    const float* W2 = (const float*)d_in[6];
    const float* b2 = (const float*)d_in[7];
    float* out = (float*)d_out;
    float* Hws = (float*)d_ws;   // [4][128][64] fp32 = 128 KiB

    mdlstm_kernel<<<NDIR * (BATCH / BT), NTHR, 0, stream>>>(x, Wx, U, bs, Hws);
    fc_kernel<<<BATCH, 1024, 0, stream>>>(Hws, W1, b1, W2, b2, out);
}

// Round 7
// 146.356 us; speedup vs baseline: 1.2271x; 1.0291x over previous
//
#include <hip/hip_runtime.h>
#include <hip/hip_bf16.h>

// 2D-MDLSTM (4 directions) + FC head for MI355X — round 22 (terminal config).
//
// R21 post-mortem: -20% MFMA work, -20% LDS A-reads, -13% conflicts -> +3 us
// (MfmaUtil 19.0 = 25*0.8*84/87: work cut, clock didn't move). The step is
// bound by its serial chain (barrier -> ds_read ~120cy -> dependent MFMA
// chain -> trans chain -> ds_write -> lgkm drain -> skew ~= 1470 cyc fixed),
// not by any pipe's throughput.
//
// Complete falsification matrix: more waves (R6-8), co-resident WGs by both
// mechanisms (R5/R10/R19/R20: work adds linearly, no cross-WG phase overlap),
// fusion/handoff (R14/R17: +48-56 us), intra-wave ILP (R13), absolute
// mapping (R16), work reduction (R21). R12 is a sharp local optimum at the
// 55-barrier dependency floor: 78 critical wave-tasks (minimum for this
// tiling), 27% padding (minimal for M-tile=16/BT=2; BT=4 lengthens the
// critical path 78->124). fc-1024 (R18) is the one verified win (-6 us).
//
// This build = R12 mdlstm VERBATIM (measured 82.9-84.3 us) + R18 fc
// (measured total 146.1 us). Budget: 84 recurrence + ~3 fc + ~59 fixed
// two-launch harness overhead.

#define GRIDN 28
#define BATCH 128
#define HID   64
#define NDIR  4
#define FC_HD 512
#define OUT_N 10
#define BT    2
#define NTHR  512
#define NSLOT 29          // 28 frontier rows + permanent-zero row (r = -1)
#define S_H   104         // f16/slot: [0,64) h | [64]=x [65]=1 [66,96)=0 | 8 pad
#define S_C   68          // float/slot: 64 c + 4 pad

typedef _Float16 f16;
typedef _Float16 f16x8 __attribute__((ext_vector_type(8)));
typedef float    f32x4 __attribute__((ext_vector_type(4)));

#define LOG2E  1.44269504088896340736f
#define LOG2E2 2.88539008177792681472f

__device__ __forceinline__ float rcpf(float x) { return __builtin_amdgcn_rcpf(x); }
__device__ __forceinline__ float ex2(float x)  { return __builtin_amdgcn_exp2f(x); }

__global__ __launch_bounds__(NTHR)
void mdlstm_kernel(const float* __restrict__ x,    // [B][28][28]
                   const float* __restrict__ Wx,   // [4][320]
                   const float* __restrict__ U,    // [4][128][320]
                   const float* __restrict__ bias, // [4][320]
                   float* __restrict__ Hout)       // [4][B][64]
{
    const int d    = blockIdx.x & 3;
    const int tile = blockIdx.x >> 2;     // 0..63 batch-pair
    const int tid  = threadIdx.x;
    const int lane = tid & 63;
    const int wave = tid >> 6;            // 0..7
    const int wm   = wave >> 2;           // tile parity 0/1
    const int wh   = wave & 3;            // h-subtile (n = wh*16 + l16)
    const int l16  = lane & 15;
    const int q    = lane >> 4;
    const int nb   = wh * 16 + l16;       // this lane's h index 0..63

    __shared__ __align__(16) f16 Fh[2][BT][NSLOT * S_H];
    __shared__ float             Fc[2][BT][NSLOT * S_C];
    __shared__ float             xs[GRIDN][GRIDN][BT];

    for (int i = tid; i < 2 * BT * NSLOT * S_H; i += NTHR) ((f16*)Fh)[i] = (f16)0.0f;
    for (int i = tid; i < 2 * BT * NSLOT * S_C; i += NTHR) ((float*)Fc)[i] = 0.0f;
    for (int i = tid; i < GRIDN * GRIDN * BT; i += NTHR) {
        int bl = i & 1, rc = i >> 1, c = rc % GRIDN, r = rc / GRIDN;
        int rr = (d & 2) ? (GRIDN - 1 - r) : r;
        int cc = (d & 1) ? (GRIDN - 1 - c) : c;
        xs[r][c][bl] = x[((tile * BT + bl) * GRIDN + rr) * GRIDN + cc];
    }

    // ---- B-fragments in registers, gate-scaled: 25 x f16x8 (100 regs)
    // sigmoid gates scaled by -log2e (sig = rcp(1+2^acc)); g gate by +2log2e.
    f16x8 bf[5][5];
#pragma unroll
    for (int g = 0; g < 5; ++g) {
        const float sc = (g == 4) ? LOG2E2 : -LOG2E;
        int n = g * 64 + nb;
#pragma unroll
        for (int ks = 0; ks < 4; ++ks) {
            f16x8 v;
            int kb = ks * 32 + q * 8;
#pragma unroll
            for (int j = 0; j < 8; ++j)
                v[j] = (f16)(sc * U[(d * 128 + kb + j) * 320 + n]);
            bf[g][ks] = v;
        }
        f16x8 v5 = {(f16)0, (f16)0, (f16)0, (f16)0, (f16)0, (f16)0, (f16)0, (f16)0};
        if (q == 0) {
            v5[0] = (f16)(sc * Wx[d * 320 + n]);
            v5[1] = (f16)(sc * bias[d * 320 + n]);
        }
        bf[g][4] = v5;
    }
    __syncthreads();   // zero-init complete

    // ones in the x-region ([65]=1) of every slot, both buffers; seed x(0,0)
    if (tid < 2 * BT * NSLOT) {
        int buf = tid / (BT * NSLOT), rem = tid % (BT * NSLOT);
        int b = rem / NSLOT, sl = rem % NSLOT;
        Fh[buf][b][sl * S_H + 65] = (f16)1.0f;
    }
    if (tid < BT) Fh[0][tid][27 * S_H + 64] = (f16)xs[0][0][tid];
    __syncthreads();

    // one anti-diagonal; br is a literal at every callsite -> const-folds
    auto step = [&](int t, int br) __attribute__((always_inline)) {
        const int bw  = br ^ 1;
        const int rlo = (t > GRIDN - 1) ? (t - (GRIDN - 1)) : 0;
        const int rhi = (t < GRIDN - 1) ? t : (GRIDN - 1);
        const int k   = rhi - rlo + 1;
        const int nM  = (2 * k + 15) >> 4;

        // stage x for diagonal t+1 into the write buffer (tail lanes of last wave)
        if (t < 2 * GRIDN - 2 && tid >= NTHR - 56) {
            int idx = tid - (NTHR - 56), b = idx & 1, j = idx >> 1;
            int rlo2 = (t + 1 > GRIDN - 1) ? (t + 1 - (GRIDN - 1)) : 0;
            int rhi2 = (t + 1 < GRIDN - 1) ? (t + 1) : (GRIDN - 1);
            if (j <= rhi2 - rlo2) {
                int r = rlo2 + j;
                Fh[bw][b][(27 - r) * S_H + 64] = (f16)xs[r][t + 1 - r][b];
            }
        }

        for (int mt = wm; mt < nM; mt += 2) {
            // ---- A fragments: task row mA -> (batch bA, grid row rA)
            int mA = mt * 16 + l16;
            int jA = mA >> 1; if (jA > k - 1) jA = k - 1;
            int bA = mA & 1;
            int slA = 27 - (rlo + jA);
            const f16* ab = &Fh[br][bA][slA * S_H];
            f16x8 a0 = *(const f16x8*)(ab + q * 8);              // h_left k 0..63
            f16x8 a1 = *(const f16x8*)(ab + 32 + q * 8);
            f16x8 a2 = *(const f16x8*)(ab + S_H + q * 8);        // h_up   k 64..127
            f16x8 a3 = *(const f16x8*)(ab + S_H + 32 + q * 8);
            f16x8 a4 = *(const f16x8*)(ab + 64 + q * 8);         // {x,1,0..} k 128..159

            // ---- epilogue addresses + c-state PRELOAD (before MFMAs: their
            // ~120 cyc LDS latency drains under the MFMA block)
            int j0  = mt * 8 + q * 2;
            int jj0 = (j0     > k - 1) ? k - 1 : j0;
            int jj1 = (j0 + 1 > k - 1) ? k - 1 : j0 + 1;
            int sl0 = 27 - (rlo + jj0);
            int sl1 = 27 - (rlo + jj1);
            const float* rp[4] = { &Fc[br][0][sl0 * S_C + nb], &Fc[br][1][sl0 * S_C + nb],
                                   &Fc[br][0][sl1 * S_C + nb], &Fc[br][1][sl1 * S_C + nb] };
            float pcl[4], pcu[4];
#pragma unroll
            for (int i = 0; i < 4; ++i) { pcl[i] = rp[i][0]; pcu[i] = rp[i][S_C]; }

            const f32x4 z4 = {0.f, 0.f, 0.f, 0.f};               // shared zero-C
            f32x4 acc[5];
#pragma unroll
            for (int g = 0; g < 5; ++g) acc[g] = __builtin_amdgcn_mfma_f32_16x16x32_f16(a4, bf[g][4], z4, 0, 0, 0);
#pragma unroll
            for (int g = 0; g < 5; ++g) acc[g] = __builtin_amdgcn_mfma_f32_16x16x32_f16(a0, bf[g][0], acc[g], 0, 0, 0);
#pragma unroll
            for (int g = 0; g < 5; ++g) acc[g] = __builtin_amdgcn_mfma_f32_16x16x32_f16(a1, bf[g][1], acc[g], 0, 0, 0);
#pragma unroll
            for (int g = 0; g < 5; ++g) acc[g] = __builtin_amdgcn_mfma_f32_16x16x32_f16(a2, bf[g][2], acc[g], 0, 0, 0);
#pragma unroll
            for (int g = 0; g < 5; ++g) acc[g] = __builtin_amdgcn_mfma_f32_16x16x32_f16(a3, bf[g][3], acc[g], 0, 0, 0);

            // ---- gates + state, BRANCHLESS, trans-merged.
            // acc0=-log2e*i  acc1=-log2e*f1  acc2=-log2e*f2  acc3=-log2e*o
            // acc4=+2log2e*g
            //   sig(i)*tanh(g)        = (tb-2)*rcp(ta*tb)
            //   sig(f1)*cl+sig(f2)*cu = (cl*tq+cu*tp)*rcp(tp*tq)
            //   sig(o)*tanh(cn)       = (te-2)*rcp(td*te), cn clamped to 22
            //     for te only (tanh(22)==1.0f exactly; prevents te=inf ->
            //     inf*0=NaN when the accumulated c exceeds 44 — the R11 bug).
            const int DC = (bw - br) * (BT * NSLOT * S_C);   // compile-time
            int ih0 = sl0 * S_H + nb, ih1 = sl1 * S_H + nb;
            f16* wh0 = &Fh[bw][0][0];
            f16* wh1 = &Fh[bw][1][0];
#pragma unroll
            for (int i = 0; i < 4; ++i) {
                float ta = 1.0f + ex2(acc[0][i]);
                float tp = 1.0f + ex2(acc[1][i]);
                float tq = 1.0f + ex2(acc[2][i]);
                float td = 1.0f + ex2(acc[3][i]);
                float tb = 1.0f + ex2(acc[4][i]);
                float cn = (tb - 2.0f) * rcpf(ta * tb)
                         + (pcl[i] * tq + pcu[i] * tp) * rcpf(tp * tq);
                float cnc = fminf(cn, 22.0f);
                float te = 1.0f + ex2(LOG2E2 * cnc);
                float hn = (te - 2.0f) * rcpf(td * te);
                *(float*)(rp[i] + DC) = cn;
                ((i & 1) ? wh1 : wh0)[(i < 2) ? ih0 : ih1] = (f16)hn;
            }
        }
        __syncthreads();
    };

    for (int tb = 0; tb < 27; ++tb) { step(2 * tb, 0); step(2 * tb + 1, 1); }
    step(54, 0);

    // final h(27,27): t=54 wrote buf 1, slot 0
    if (tid < BT * HID) {
        int bl = tid >> 6, h = tid & 63;
        Hout[(d * BATCH + tile * BT + bl) * HID + h] = (float)Fh[1][bl][h];
    }
}

// FC head (R18, the verified win): one WG of 1024 threads per batch row
// (16 waves/WG, 128 WGs -> 8 waves/CU on 128 CUs). z1: 1 col/thread, K
// split in half (128-deep load chain, 4x TLP); halves combine via LDS.
__global__ __launch_bounds__(1024)
void fc_kernel(const float* __restrict__ Hin,  // [4][B][64]
               const float* __restrict__ W1, const float* __restrict__ b1,
               const float* __restrict__ W2, const float* __restrict__ b2,
               float* __restrict__ out)        // [B][10]
{
    const int b   = blockIdx.x;
    const int tid = threadIdx.x;
    __shared__ float hrow[NDIR * HID];
    __shared__ float psum[2][FC_HD];
    __shared__ float z1[FC_HD];
    __shared__ float ps[32][16];
    __shared__ float z2[16];

    if (tid < NDIR * HID)
        hrow[tid] = Hin[(tid >> 6) * (BATCH * HID) + b * HID + (tid & 63)];
    __syncthreads();

    {
        int col = tid & (FC_HD - 1);
        int hf  = tid >> 9;
        int f0  = hf * 128;
        float s = 0.0f;
#pragma unroll 16
        for (int f = 0; f < 128; ++f)
            s += hrow[f0 + f] * W1[(f0 + f) * FC_HD + col];
        psum[hf][col] = s;
    }
    __syncthreads();

    if (tid < FC_HD)
        z1[tid] = fmaxf(psum[0][tid] + psum[1][tid] + b1[tid], 0.0f);
    __syncthreads();

    if (tid < 512) {
        int j = tid & 15, sl = tid >> 4;
        float s = 0.0f;
        if (j < OUT_N) {
#pragma unroll
            for (int i = 0; i < 16; ++i) {
                int kk = sl * 16 + i;
                s += z1[kk] * W2[kk * OUT_N + j];
            }
        }
        ps[sl][j] = s;
    }
    __syncthreads();

    if (tid < OUT_N) {
        float s = b2[tid];
#pragma unroll
        for (int sl = 0; sl < 32; ++sl) s += ps[sl][tid];
        z2[tid] = s;
    }
    __syncthreads();

    if (tid == 0) {
        float m = z2[0];
        for (int j = 1; j < OUT_N; ++j) m = fmaxf(m, z2[j]);
        float sum = 0.0f, e[OUT_N];
        for (int j = 0; j < OUT_N; ++j) { e[j] = __expf(z2[j] - m); sum += e[j]; }
        float inv = 1.0f / sum;
        for (int j = 0; j < OUT_N; ++j) out[b * OUT_N + j] = e[j] * inv;
    }
}

extern "C" void kernel_launch(void* const* d_in, const int* in_sizes, int n_in,
                              void* d_out, int out_size, void* d_ws, size_t ws_size,
                              hipStream_t stream) {
    const float* x  = (const float*)d_in[0];
    const float* Wx = (const float*)d_in[1];
    const float* U  = (const float*)d_in[2];
    const float* bs = (const float*)d_in[3];
    const float* W1 = (const float*)d_in[4];
    const float* b1 = (const float*)d_in[5];
    const float* W2 = (const float*)d_in[6];
    const float* b2 = (const float*)d_in[7];
    float* out = (float*)d_out;
    float* Hws = (float*)d_ws;   // [4][128][64] fp32 = 128 KiB

    mdlstm_kernel<<<NDIR * (BATCH / BT), NTHR, 0, stream>>>(x, Wx, U, bs, Hws);
    fc_kernel<<<BATCH, 1024, 0, stream>>>(Hws, W1, b1, W2, b2, out);
}